// Round 1
// baseline (130.030 us; speedup 1.0000x reference)
//
#include <hip/hip_runtime.h>

// Problem constants (fixed by setup_inputs): B=4, C=32, H=64, W=128, D=192/4=48.
#define B_  4
#define C_  32
#define H_  64
#define W_  128
#define D_  48

// Output: (B, 2C, D, H, W) float32.
//   ch <  C : out = left[b][ch][h][w]                    (broadcast over d)
//   ch >= C : out = (w+d < W) ? right[b][ch-C][h][w+d] : 0
//
// One thread per output float4. Block 256 = 32 (w4) x 8 (h-sub).
// Grid (H/8, D, B*2C) -> no integer div/mod anywhere.
__global__ __launch_bounds__(256) void CostVolume_66529043415444_kernel(
    const float* __restrict__ left,
    const float* __restrict__ right,
    float* __restrict__ out)
{
    const int tid = threadIdx.x;
    const int w4  = tid & 31;            // float4 index within row: 0..31
    const int hs  = tid >> 5;            // 0..7
    const int h   = (int)blockIdx.x * 8 + hs;
    const int d   = (int)blockIdx.y;     // 0..47
    const int z   = (int)blockIdx.z;     // b*64 + ch
    const int ch  = z & 63;
    const int b   = z >> 6;

    // out float4 offset: (((z)*D + d)*H + h)*32 + w4
    float4* __restrict__ out4 = reinterpret_cast<float4*>(out);
    const size_t oidx = ((((size_t)z * D_ + d) * H_ + h) << 5) + w4;

    if (ch < C_) {
        // left broadcast: aligned float4 load (L2-resident after first d)
        const float4* __restrict__ l4 = reinterpret_cast<const float4*>(left);
        const size_t lidx = ((((size_t)b * C_ + ch) * H_ + h) << 5) + w4;
        out4[oidx] = l4[lidx];
    } else {
        const int c = ch - C_;
        const float* __restrict__ row = right + (((size_t)b * C_ + c) * H_ + h) * W_;
        const int w0 = (w4 << 2) + d;    // shifted, generally unaligned
        float4 v;
        v.x = (w0 + 0 < W_) ? row[w0 + 0] : 0.0f;
        v.y = (w0 + 1 < W_) ? row[w0 + 1] : 0.0f;
        v.z = (w0 + 2 < W_) ? row[w0 + 2] : 0.0f;
        v.w = (w0 + 3 < W_) ? row[w0 + 3] : 0.0f;
        out4[oidx] = v;
    }
}

extern "C" void kernel_launch(void* const* d_in, const int* in_sizes, int n_in,
                              void* d_out, int out_size, void* d_ws, size_t ws_size,
                              hipStream_t stream) {
    const float* left  = (const float*)d_in[0];
    const float* right = (const float*)d_in[1];
    float* out = (float*)d_out;

    dim3 block(256);
    dim3 grid(H_ / 8, D_, B_ * 2 * C_);   // (8, 48, 256) = 98304 blocks
    CostVolume_66529043415444_kernel<<<grid, block, 0, stream>>>(left, right, out);
}

// Round 3
// 68.571 us; speedup vs baseline: 1.8963x; 1.8963x over previous
//
#include <hip/hip_runtime.h>

// Problem constants (fixed by setup_inputs): B=4, C=32, H=64, W=128, D=192/4=48.
#define B_  4
#define C_  32
#define H_  64
#define W_  128
#define D_  48
#define HS_ 8          // h-rows per block
#define ROWF_ 200      // LDS floats per row: 128 data + 64 zero tail + 8 bank-shift pad

// Native clang vector (usable with __builtin_nontemporal_store, unlike HIP's float4)
typedef float f32x4 __attribute__((ext_vector_type(4)));

// Output: (B, 2C, D, H, W) float32.
//   ch <  C : out = left[b][ch][h][w]                      (broadcast over d)
//   ch >= C : out = (w+d < W) ? right[b][ch-C][h][w+d] : 0
//
// One block per (z = b*2C+ch, 8-row h-stripe); block loops over ALL 48 d-planes
// so each thread writes 48 float4 = 768 B. Grid = (8, 256) = 2048 blocks =
// 8 blocks/CU = 32 waves/CU. Right rows staged in LDS with a zeroed tail ->
// no boundary branches; the shift-by-d gather is 2 aligned ds_read_b128 +
// register shuffles per 4 d-values. Nontemporal output stores keep the 402 MB
// write stream from evicting the 8 MB of L2-resident inputs.
__global__ __launch_bounds__(256) void CostVolume_66529043415444_kernel(
    const float* __restrict__ left,
    const float* __restrict__ right,
    float* __restrict__ out)
{
    const int tid = threadIdx.x;
    const int w4  = tid & 31;            // float4 index within row: 0..31
    const int hs  = tid >> 5;            // 0..7
    const int h   = (int)blockIdx.x * HS_ + hs;
    const int z   = (int)blockIdx.y;     // b*64 + ch
    const int ch  = z & 63;
    const int b   = z >> 6;

    f32x4* __restrict__ out4 = reinterpret_cast<f32x4*>(out);
    // out float4 offset for (z, d, h, w4): ((z*D + d)*H + h)*32 + w4
    const size_t obase = (((size_t)z * D_) * H_ + h) * (W_ / 4) + w4;
    const size_t dstr  = (size_t)H_ * (W_ / 4);   // 2048 float4 per d-plane

    if (ch < C_) {
        // left broadcast: load the row fragment once, store it to all 48 d-planes
        const f32x4* __restrict__ l4 = reinterpret_cast<const f32x4*>(left);
        const f32x4 v = l4[(((size_t)b * C_ + ch) * H_ + h) * (W_ / 4) + w4];
        #pragma unroll
        for (int d = 0; d < D_; ++d)
            __builtin_nontemporal_store(v, &out4[obase + (size_t)d * dstr]);
    } else {
        __shared__ __align__(16) float rows[HS_][ROWF_];
        const int c = ch - C_;
        const f32x4* __restrict__ r4 =
            reinterpret_cast<const f32x4*>(right + (((size_t)b * C_ + c) * H_ + h) * W_);
        // stage row into LDS (one float4 per thread), zero the tail 128..191
        const f32x4 rv = r4[w4];
        *reinterpret_cast<f32x4*>(&rows[hs][w4 * 4]) = rv;
        if (w4 < 16) {
            const f32x4 z4 = {0.f, 0.f, 0.f, 0.f};
            *reinterpret_cast<f32x4*>(&rows[hs][W_ + w4 * 4]) = z4;
        }
        __syncthreads();

        #pragma unroll
        for (int d0 = 0; d0 < D_; d0 += 4) {
            // aligned window: floats [4*w4 + d0 .. 4*w4 + d0 + 7]
            const int k = w4 + (d0 >> 2);
            const f32x4 a  = *reinterpret_cast<const f32x4*>(&rows[hs][k * 4]);
            const f32x4 bb = *reinterpret_cast<const f32x4*>(&rows[hs][k * 4 + 4]);
            const f32x4 v0 = a;
            const f32x4 v1 = {a.y, a.z, a.w, bb.x};
            const f32x4 v2 = {a.z, a.w, bb.x, bb.y};
            const f32x4 v3 = {a.w, bb.x, bb.y, bb.z};
            __builtin_nontemporal_store(v0, &out4[obase + (size_t)(d0 + 0) * dstr]);
            __builtin_nontemporal_store(v1, &out4[obase + (size_t)(d0 + 1) * dstr]);
            __builtin_nontemporal_store(v2, &out4[obase + (size_t)(d0 + 2) * dstr]);
            __builtin_nontemporal_store(v3, &out4[obase + (size_t)(d0 + 3) * dstr]);
        }
    }
}

extern "C" void kernel_launch(void* const* d_in, const int* in_sizes, int n_in,
                              void* d_out, int out_size, void* d_ws, size_t ws_size,
                              hipStream_t stream) {
    const float* left  = (const float*)d_in[0];
    const float* right = (const float*)d_in[1];
    float* out = (float*)d_out;

    dim3 block(256);
    dim3 grid(H_ / HS_, B_ * 2 * C_);   // (8, 256) = 2048 blocks
    CostVolume_66529043415444_kernel<<<grid, block, 0, stream>>>(left, right, out);
}